// Round 2
// baseline (63325.903 us; speedup 1.0000x reference)
//
#include <hip/hip_runtime.h>
#include <math.h>

#define HID 512
#define FEAT 128
#define SEQL 512
#define PREDL 128
#define LDSP 17
#define NWG 256

__device__ __forceinline__ float sigf_(float x) { return 1.0f / (1.0f + __expf(-x)); }
__device__ __forceinline__ float tanh_(float x) {
  float ax = fabsf(x);
  float e2 = __expf(-2.0f * ax);
  return copysignf((1.0f - e2) / (1.0f + e2), x);
}

// Agent-scope (cross-XCD coherent) load/store: sc-bit per-access, leaves L2 intact.
__device__ __forceinline__ float ldg_sc(const float* p) {
  return __hip_atomic_load(p, __ATOMIC_RELAXED, __HIP_MEMORY_SCOPE_AGENT);
}
__device__ __forceinline__ void stg_sc(float* p, float v) {
  __hip_atomic_store(p, v, __ATOMIC_RELAXED, __HIP_MEMORY_SCOPE_AGENT);
}

// Hierarchical grid barrier: 8 per-XCD counters -> root -> generation flag.
// Monotonic counters; phase starts at 1. 256 WGs, 32 per XCD residue.
__device__ __forceinline__ void grid_bar(int* bar, int wg, int phase) {
  __syncthreads();  // drains vmcnt: all threads' sc-stores are at coherence point
  if (threadIdx.x == 0) {
    int* cxt = bar + (wg & 7) * 32;
    const int a = __hip_atomic_fetch_add(cxt, 1, __ATOMIC_ACQ_REL, __HIP_MEMORY_SCOPE_AGENT);
    if (a == 32 * phase - 1) {
      const int r = __hip_atomic_fetch_add(bar + 8 * 32, 1, __ATOMIC_ACQ_REL, __HIP_MEMORY_SCOPE_AGENT);
      if (r == 8 * phase - 1)
        __hip_atomic_store(bar + 9 * 32, phase, __ATOMIC_RELEASE, __HIP_MEMORY_SCOPE_AGENT);
    }
    while (__hip_atomic_load(bar + 9 * 32, __ATOMIC_ACQUIRE, __HIP_MEMORY_SCOPE_AGENT) < phase)
      __builtin_amdgcn_s_sleep(1);
  }
  __syncthreads();
}

// ---- staging helpers (all 512 threads cooperate) --------------------------
__device__ __forceinline__ void stage_tile512(float* dst, const float* src,
                                              int b0, int tid) {
#pragma unroll
  for (int idx = tid; idx < 16 * HID; idx += 512) {  // 16 iters
    const int k = idx & (HID - 1);
    const int bb = idx >> 9;
    dst[k * LDSP + bb] = ldg_sc(src + (size_t)(b0 + bb) * HID + k);
  }
}
__device__ __forceinline__ void stage_x(float* dst, const float* x, int t,
                                        int b0, int tid) {
#pragma unroll
  for (int idx = tid; idx < 16 * FEAT; idx += 512) {  // 4 iters
    const int k = idx & (FEAT - 1);
    const int bb = idx >> 7;
    dst[k * LDSP + bb] = x[((size_t)(b0 + bb) * SEQL + t) * FEAT + k];
  }
}

__device__ __forceinline__ void act_store(float acc0, float acc1, float acc2,
                                          float acc3, float& c_reg,
                                          float* Hout, size_t ci) {
  const float ig = sigf_(acc0), fg = sigf_(acc1);
  const float gg = tanh_(acc2), og = sigf_(acc3);
  const float cn = fg * c_reg + ig * gg;
  c_reg = cn;
  stg_sc(Hout + ci, og * tanh_(cn));
}

// gates = init + sA@WA^T (K=512) + sH@WH^T (K=512)
__device__ __forceinline__ void cell512(
    const float* __restrict__ sA,
    const float4* __restrict__ a0, const float4* __restrict__ a1,
    const float4* __restrict__ a2, const float4* __restrict__ a3,
    const float* __restrict__ sH,
    const float4* __restrict__ h0p, const float4* __restrict__ h1p,
    const float4* __restrict__ h2p, const float4* __restrict__ h3p,
    float i0, float i1, float i2, float i3,
    int b, float& c_reg, float* __restrict__ Hout, size_t ci) {
  float acc0 = i0, acc1 = i1, acc2 = i2, acc3 = i3;
#pragma unroll 2
  for (int k4 = 0; k4 < HID / 4; ++k4) {
    const int k = k4 * 4;
    const float A0 = sA[k * LDSP + b], A1 = sA[(k + 1) * LDSP + b];
    const float A2 = sA[(k + 2) * LDSP + b], A3 = sA[(k + 3) * LDSP + b];
    const float H0 = sH[k * LDSP + b], H1 = sH[(k + 1) * LDSP + b];
    const float H2 = sH[(k + 2) * LDSP + b], H3 = sH[(k + 3) * LDSP + b];
    float4 w;
    w = a0[k4];  acc0 += w.x * A0 + w.y * A1 + w.z * A2 + w.w * A3;
    w = a1[k4];  acc1 += w.x * A0 + w.y * A1 + w.z * A2 + w.w * A3;
    w = a2[k4];  acc2 += w.x * A0 + w.y * A1 + w.z * A2 + w.w * A3;
    w = a3[k4];  acc3 += w.x * A0 + w.y * A1 + w.z * A2 + w.w * A3;
    w = h0p[k4]; acc0 += w.x * H0 + w.y * H1 + w.z * H2 + w.w * H3;
    w = h1p[k4]; acc1 += w.x * H0 + w.y * H1 + w.z * H2 + w.w * H3;
    w = h2p[k4]; acc2 += w.x * H0 + w.y * H1 + w.z * H2 + w.w * H3;
    w = h3p[k4]; acc3 += w.x * H0 + w.y * H1 + w.z * H2 + w.w * H3;
  }
  act_store(acc0, acc1, acc2, acc3, c_reg, Hout, ci);
}

// LSTM0 teacher cell: gates = init + sE@wih0^T (K=128) + sH@whh0^T (K=512)
__device__ __forceinline__ void cell0tf(
    const float* __restrict__ sE, const float* __restrict__ sH,
    const float4* __restrict__ e0, const float4* __restrict__ e1,
    const float4* __restrict__ e2, const float4* __restrict__ e3,
    const float4* __restrict__ h0p, const float4* __restrict__ h1p,
    const float4* __restrict__ h2p, const float4* __restrict__ h3p,
    float i0, float i1, float i2, float i3,
    int b, float& c_reg, float* __restrict__ Hout, size_t ci) {
  float acc0 = i0, acc1 = i1, acc2 = i2, acc3 = i3;
#pragma unroll 2
  for (int k4 = 0; k4 < HID / 4; ++k4) {
    const int k = k4 * 4;
    const float H0 = sH[k * LDSP + b], H1 = sH[(k + 1) * LDSP + b];
    const float H2 = sH[(k + 2) * LDSP + b], H3 = sH[(k + 3) * LDSP + b];
    float4 w;
    w = h0p[k4]; acc0 += w.x * H0 + w.y * H1 + w.z * H2 + w.w * H3;
    w = h1p[k4]; acc1 += w.x * H0 + w.y * H1 + w.z * H2 + w.w * H3;
    w = h2p[k4]; acc2 += w.x * H0 + w.y * H1 + w.z * H2 + w.w * H3;
    w = h3p[k4]; acc3 += w.x * H0 + w.y * H1 + w.z * H2 + w.w * H3;
  }
#pragma unroll 2
  for (int k4 = 0; k4 < FEAT / 4; ++k4) {
    const int k = k4 * 4;
    const float E0 = sE[k * LDSP + b], E1 = sE[(k + 1) * LDSP + b];
    const float E2 = sE[(k + 2) * LDSP + b], E3 = sE[(k + 3) * LDSP + b];
    float4 w;
    w = e0[k4]; acc0 += w.x * E0 + w.y * E1 + w.z * E2 + w.w * E3;
    w = e1[k4]; acc1 += w.x * E0 + w.y * E1 + w.z * E2 + w.w * E3;
    w = e2[k4]; acc2 += w.x * E0 + w.y * E1 + w.z * E2 + w.w * E3;
    w = e3[k4]; acc3 += w.x * E0 + w.y * E1 + w.z * E2 + w.w * E3;
  }
  act_store(acc0, acc1, acc2, acc3, c_reg, Hout, ci);
}

__device__ __forceinline__ void dec_body(const float* __restrict__ sH1,
                                         const float4* __restrict__ decr,
                                         float decb, int b0, int bd, int jdec,
                                         float* __restrict__ out, int step) {
  float acc = decb;
#pragma unroll 2
  for (int k4 = 0; k4 < HID / 4; ++k4) {
    const int k = k4 * 4;
    const float4 w = decr[k4];
    acc += w.x * sH1[k * LDSP + bd] + w.y * sH1[(k + 1) * LDSP + bd] +
           w.z * sH1[(k + 2) * LDSP + bd] + w.w * sH1[(k + 3) * LDSP + bd];
  }
  out[((size_t)(b0 + bd) * PREDL + step) * FEAT + jdec] = acc;
}

// ---------------------------------------------------------------------------
// Persistent kernel: 256 WGs x 512 threads. LDS 87KB -> exactly 1 WG/CU.
// half 0 (tid<256): LSTM0 tile. half 1: LSTM1 tile (+64 WGs decode in AR).
// ---------------------------------------------------------------------------
__global__ __launch_bounds__(512, 2) void k_persist(
    const float* __restrict__ x,
    const float* __restrict__ enc_w, const float* __restrict__ enc_b,
    const float* __restrict__ wih0, const float* __restrict__ whh0,
    const float* __restrict__ bih0, const float* __restrict__ bhh0,
    const float* __restrict__ wih1, const float* __restrict__ whh1,
    const float* __restrict__ bih1, const float* __restrict__ bhh1,
    const float* __restrict__ dec_w, const float* __restrict__ dec_b,
    const float* __restrict__ Wcomp, const float* __restrict__ bcomp,
    float* __restrict__ h0A, float* __restrict__ h0B,
    float* __restrict__ h1A, float* __restrict__ h1B,
    int* __restrict__ bar, float* __restrict__ out) {
  __shared__ float s_h0[HID * LDSP];
  __shared__ float s_h1[HID * LDSP];
  __shared__ float s_x[FEAT * LDSP];
  __shared__ float s_e[FEAT * LDSP];

  const int wg = blockIdx.x;
  const int tid = threadIdx.x;
  const int ut = (wg & 7) * 4 + ((wg >> 3) & 3);  // XCD-affine unit tile
  const int bt = wg >> 5;
  const int b0 = bt * 16;
  const int half = tid >> 8;
  const int t8 = tid & 255;
  const int u = t8 >> 4, b = t8 & 15;
  const int ug = ut * 16 + u;
  const size_t ci = (size_t)(b0 + b) * HID + ug;

  float* h0buf[2] = {h0A, h0B};
  float* h1buf[2] = {h1A, h1B};

  // hoisted weight-row pointers + bias sums (held in VGPRs for all 639 steps)
  const float4* e0p = (const float4*)(wih0 + (size_t)ug * FEAT);
  const float4* e1p = (const float4*)(wih0 + (size_t)(512 + ug) * FEAT);
  const float4* e2p = (const float4*)(wih0 + (size_t)(1024 + ug) * FEAT);
  const float4* e3p = (const float4*)(wih0 + (size_t)(1536 + ug) * FEAT);
  const float4* H00 = (const float4*)(whh0 + (size_t)ug * HID);
  const float4* H01 = (const float4*)(whh0 + (size_t)(512 + ug) * HID);
  const float4* H02 = (const float4*)(whh0 + (size_t)(1024 + ug) * HID);
  const float4* H03 = (const float4*)(whh0 + (size_t)(1536 + ug) * HID);
  const float4* Wc0 = (const float4*)(Wcomp + (size_t)ug * HID);
  const float4* Wc1 = (const float4*)(Wcomp + (size_t)(512 + ug) * HID);
  const float4* Wc2 = (const float4*)(Wcomp + (size_t)(1024 + ug) * HID);
  const float4* Wc3 = (const float4*)(Wcomp + (size_t)(1536 + ug) * HID);
  const float4* I10 = (const float4*)(wih1 + (size_t)ug * HID);
  const float4* I11 = (const float4*)(wih1 + (size_t)(512 + ug) * HID);
  const float4* I12 = (const float4*)(wih1 + (size_t)(1024 + ug) * HID);
  const float4* I13 = (const float4*)(wih1 + (size_t)(1536 + ug) * HID);
  const float4* H10 = (const float4*)(whh1 + (size_t)ug * HID);
  const float4* H11 = (const float4*)(whh1 + (size_t)(512 + ug) * HID);
  const float4* H12 = (const float4*)(whh1 + (size_t)(1024 + ug) * HID);
  const float4* H13 = (const float4*)(whh1 + (size_t)(1536 + ug) * HID);
  const float bt00 = bih0[ug] + bhh0[ug];
  const float bt01 = bih0[512 + ug] + bhh0[512 + ug];
  const float bt02 = bih0[1024 + ug] + bhh0[1024 + ug];
  const float bt03 = bih0[1536 + ug] + bhh0[1536 + ug];
  const float ba00 = bt00 + bcomp[ug];
  const float ba01 = bt01 + bcomp[512 + ug];
  const float ba02 = bt02 + bcomp[1024 + ug];
  const float ba03 = bt03 + bcomp[1536 + ug];
  const float b10 = bih1[ug] + bhh1[ug];
  const float b11 = bih1[512 + ug] + bhh1[512 + ug];
  const float b12 = bih1[1024 + ug] + bhh1[1024 + ug];
  const float b13 = bih1[1536 + ug] + bhh1[1536 + ug];

  // decoder role constants
  const int is_dec = (half == 1) && (((wg >> 3) & 3) == 0);
  const int jdec = (wg & 7) * 16 + (t8 >> 4);
  const int bd = t8 & 15;
  const float4* decr = (const float4*)(dec_w + (size_t)jdec * HID);
  const float decb = dec_b[jdec];

  float c_reg = 0.0f;  // c0 (half 0) or c1 (half 1), in-register for all steps
  int ph = 0;

  // ---- teacher-forced phase: tick t = LSTM0(t) || LSTM1(t-1) --------------
  for (int t = 0; t < SEQL; ++t) {
    const float* h0in = h0buf[(t + 1) & 1];
    float* h0out = h0buf[t & 1];
    const float* h1in = h1buf[t & 1];
    float* h1out = h1buf[(t + 1) & 1];

    stage_tile512(s_h0, h0in, b0, tid);
    stage_tile512(s_h1, h1in, b0, tid);
    stage_x(s_x, x, t, b0, tid);
    __syncthreads();

    // cooperative encoder: e = x_t @ enc_w^T + enc_b (all 512 threads)
    {
      const int be = tid & 15, jg = tid >> 4;  // jg 0..31
#pragma unroll
      for (int jj = 0; jj < 4; ++jj) {
        const int j = jg * 4 + jj;
        float acc = enc_b[j];
        const float4* wr = (const float4*)(enc_w + (size_t)j * FEAT);
#pragma unroll 4
        for (int k4 = 0; k4 < FEAT / 4; ++k4) {
          const float4 w = wr[k4];
          const int k = k4 * 4;
          acc += w.x * s_x[k * LDSP + be] + w.y * s_x[(k + 1) * LDSP + be] +
                 w.z * s_x[(k + 2) * LDSP + be] + w.w * s_x[(k + 3) * LDSP + be];
        }
        s_e[j * LDSP + be] = acc;
      }
    }
    __syncthreads();

    if (half == 0) {
      cell0tf(s_e, s_h0, e0p, e1p, e2p, e3p, H00, H01, H02, H03,
              bt00, bt01, bt02, bt03, b, c_reg, h0out, ci);
    } else if (t > 0) {
      cell512(s_h0, I10, I11, I12, I13, s_h1, H10, H11, H12, H13,
              b10, b11, b12, b13, b, c_reg, h1out, ci);
    }
    grid_bar(bar, wg, ++ph);
  }

  // ---- LSTM1(511): A = h0(511)=h0buf[1], Hin = h1(510)=h1buf[0] -----------
  stage_tile512(s_h0, h0buf[1], b0, tid);
  stage_tile512(s_h1, h1buf[0], b0, tid);
  __syncthreads();
  if (half == 1) {
    cell512(s_h0, I10, I11, I12, I13, s_h1, H10, H11, H12, H13,
            b10, b11, b12, b13, b, c_reg, h1buf[1], ci);
  }
  grid_bar(bar, wg, ++ph);

  // ---- autoregressive phase ----------------------------------------------
  for (int t = SEQL; t < SEQL + PREDL - 1; ++t) {
    const float* h1prev = h1buf[(t + 1) & 1];
    const float* h0prev = h0buf[(t + 1) & 1];
    float* h0cur = h0buf[t & 1];
    float* h1cur = h1buf[t & 1];

    // phase 1: LSTM0-AR(t) (half 0) + decode out step t-512 (64 dec WGs)
    stage_tile512(s_h1, h1prev, b0, tid);
    stage_tile512(s_h0, h0prev, b0, tid);
    __syncthreads();
    if (half == 0) {
      cell512(s_h1, Wc0, Wc1, Wc2, Wc3, s_h0, H00, H01, H02, H03,
              ba00, ba01, ba02, ba03, b, c_reg, h0cur, ci);
    } else if (is_dec) {
      dec_body(s_h1, decr, decb, b0, bd, jdec, out, t - SEQL);
    }
    grid_bar(bar, wg, ++ph);

    // phase 2: LSTM1(t): A = h0cur, Hin = h1prev (still in s_h1)
    stage_tile512(s_h0, h0cur, b0, tid);
    __syncthreads();
    if (half == 1) {
      cell512(s_h0, I10, I11, I12, I13, s_h1, H10, H11, H12, H13,
              b10, b11, b12, b13, b, c_reg, h1cur, ci);
    }
    grid_bar(bar, wg, ++ph);
  }

  // ---- final output: decode h1(638) = h1buf[0], step 127 ------------------
  stage_tile512(s_h1, h1buf[0], b0, tid);
  __syncthreads();
  if (is_dec) {
    dec_body(s_h1, decr, decb, b0, bd, jdec, out, PREDL - 1);
  }
}

// ----- prologue: composite weight/bias (unchanged, verified round 0) -------
__global__ void k_b1(const float* __restrict__ enc_w,
                     const float* __restrict__ dec_w, float* __restrict__ B1) {
  const int idx = blockIdx.x * 256 + threadIdx.x;
  const int j = idx >> 9, m = idx & 511;
  float acc = 0.0f;
  for (int k = 0; k < FEAT; ++k) acc += enc_w[j * FEAT + k] * dec_w[k * HID + m];
  B1[idx] = acc;
}
__global__ void k_wcomp(const float* __restrict__ wih0,
                        const float* __restrict__ B1, float* __restrict__ W) {
  const size_t idx = (size_t)blockIdx.x * 256 + threadIdx.x;
  const int n = (int)(idx >> 9), m = (int)(idx & 511);
  float acc = 0.0f;
  for (int k = 0; k < FEAT; ++k) acc += wih0[n * FEAT + k] * B1[k * HID + m];
  W[idx] = acc;
}
__global__ void k_te(const float* __restrict__ enc_w,
                     const float* __restrict__ enc_b,
                     const float* __restrict__ dec_b, float* __restrict__ te) {
  const int j = threadIdx.x;
  float acc = enc_b[j];
  for (int k = 0; k < FEAT; ++k) acc += dec_b[k] * enc_w[j * FEAT + k];
  te[j] = acc;
}
__global__ void k_bcomp(const float* __restrict__ wih0,
                        const float* __restrict__ te, float* __restrict__ bc) {
  const int n = blockIdx.x * 256 + threadIdx.x;
  float acc = 0.0f;
  for (int j = 0; j < FEAT; ++j) acc += wih0[n * FEAT + j] * te[j];
  bc[n] = acc;
}

// ---------------------------------------------------------------------------
extern "C" void kernel_launch(void* const* d_in, const int* in_sizes, int n_in,
                              void* d_out, int out_size, void* d_ws,
                              size_t ws_size, hipStream_t stream) {
  const float* x     = (const float*)d_in[0];
  const float* enc_w = (const float*)d_in[1];
  const float* enc_b = (const float*)d_in[2];
  const float* dec_w = (const float*)d_in[3];
  const float* dec_b = (const float*)d_in[4];
  const float* wih0  = (const float*)d_in[5];
  const float* whh0  = (const float*)d_in[6];
  const float* bih0  = (const float*)d_in[7];
  const float* bhh0  = (const float*)d_in[8];
  const float* wih1  = (const float*)d_in[9];
  const float* whh1  = (const float*)d_in[10];
  const float* bih1  = (const float*)d_in[11];
  const float* bhh1  = (const float*)d_in[12];
  float* out = (float*)d_out;

  float* ws = (float*)d_ws;
  float* h0b0  = ws;                     // 2 x 65536
  float* h1b0  = ws + 131072;            // 2 x 65536
  int*   bar   = (int*)(ws + 262144);    // 1024 ints
  float* Wcomp = ws + 263168;            // 1048576
  float* B1    = ws + 1311744;           // 65536
  float* te    = ws + 1377280;           // 128
  float* bcomp = ws + 1377408;           // 2048

  // zero h states + barrier counters (re-zeroed every replay via the graph)
  hipMemsetAsync(ws, 0, (size_t)263168 * sizeof(float), stream);

  k_b1<<<256, 256, 0, stream>>>(enc_w, dec_w, B1);
  k_wcomp<<<4096, 256, 0, stream>>>(wih0, B1, Wcomp);
  k_te<<<1, 128, 0, stream>>>(enc_w, enc_b, dec_b, te);
  k_bcomp<<<8, 256, 0, stream>>>(wih0, te, bcomp);

  k_persist<<<NWG, 512, 0, stream>>>(
      x, enc_w, enc_b, wih0, whh0, bih0, bhh0, wih1, whh1, bih1, bhh1,
      dec_w, dec_b, Wcomp, bcomp,
      h0b0, h0b0 + 65536, h1b0, h1b0 + 65536, bar, out);
}

// Round 3
// 38402.878 us; speedup vs baseline: 1.6490x; 1.6490x over previous
//
#include <hip/hip_runtime.h>
#include <math.h>

#define HID 512
#define FEAT 128
#define SEQL 512
#define PREDL 128
#define NWG 256
#define HK 516   // LDS row stride (floats) for h tiles: 516%32==4 -> 2-way max
#define EK 132   // LDS row stride for x/e tiles

__device__ __forceinline__ float sigf_(float x) { return 1.0f / (1.0f + __expf(-x)); }
__device__ __forceinline__ float tanh_(float x) {
  float ax = fabsf(x);
  float e2 = __expf(-2.0f * ax);
  return copysignf((1.0f - e2) / (1.0f + e2), x);
}

// Coherent (device-scope, L2-bypassing, NON-invalidating) scalar store.
__device__ __forceinline__ void stg_sc(float* p, float v) {
  __hip_atomic_store(p, v, __ATOMIC_RELAXED, __HIP_MEMORY_SCOPE_AGENT);
}

// ---------------------------------------------------------------------------
// bt-local barrier: 32 WGs per group, relaxed atomics only (no cache inv).
// Correctness: __syncthreads drains vmcnt(0) -> all sc-stores at coherence
// point before the arrival RMW (same-thread program order). Consumers' sc
// loads bypass L1/L2, so no acquire/invalidate is needed anywhere.
// ---------------------------------------------------------------------------
__device__ __forceinline__ void bar_arrive(int* __restrict__ bar, int grp,
                                           int phase, int tid, bool& last) {
  __syncthreads();
  if (tid == 0) {
    const int a = __hip_atomic_fetch_add(bar + grp * 32, 1, __ATOMIC_RELAXED,
                                         __HIP_MEMORY_SCOPE_AGENT);
    last = (a == 32 * phase - 1);
    if (last)
      __hip_atomic_store(bar + 512 + grp * 32, phase, __ATOMIC_RELAXED,
                         __HIP_MEMORY_SCOPE_AGENT);
  }
  asm volatile("" ::: "memory");
}
__device__ __forceinline__ void bar_wait(int* __restrict__ bar, int grp,
                                         int phase, int tid, bool last) {
  asm volatile("" ::: "memory");
  if (tid == 0 && !last) {
    while (__hip_atomic_load(bar + 512 + grp * 32, __ATOMIC_RELAXED,
                             __HIP_MEMORY_SCOPE_AGENT) < phase)
      __builtin_amdgcn_s_sleep(1);
  }
  __syncthreads();
}

// ---------------------------------------------------------------------------
// Stage h tile: global transposed h[k][128b] -> LDS [16b][HK], via coherent
// dwordx4 loads (sc0 sc1: bypass L1/L2, read the L3 coherence point).
// ---------------------------------------------------------------------------
__device__ __forceinline__ void stage_h(float* __restrict__ dst,
                                        const float* __restrict__ src,
                                        int b0, int tid) {
  const int kb = tid >> 2;          // 0..127
  const int bq = (tid & 3) * 4;     // 0,4,8,12
  const float* p0 = src + ((size_t)kb) * 128 + b0 + bq;
  const float* p1 = src + ((size_t)kb + 128) * 128 + b0 + bq;
  const float* p2 = src + ((size_t)kb + 256) * 128 + b0 + bq;
  const float* p3 = src + ((size_t)kb + 384) * 128 + b0 + bq;
  float4 r0, r1, r2, r3;
  asm volatile(
      "global_load_dwordx4 %0, %4, off sc0 sc1\n\t"
      "global_load_dwordx4 %1, %5, off sc0 sc1\n\t"
      "global_load_dwordx4 %2, %6, off sc0 sc1\n\t"
      "global_load_dwordx4 %3, %7, off sc0 sc1\n\t"
      "s_waitcnt vmcnt(0)"
      : "=&v"(r0), "=&v"(r1), "=&v"(r2), "=&v"(r3)
      : "v"(p0), "v"(p1), "v"(p2), "v"(p3)
      : "memory");
  dst[(bq + 0) * HK + kb] = r0.x;  dst[(bq + 1) * HK + kb] = r0.y;
  dst[(bq + 2) * HK + kb] = r0.z;  dst[(bq + 3) * HK + kb] = r0.w;
  dst[(bq + 0) * HK + kb + 128] = r1.x;  dst[(bq + 1) * HK + kb + 128] = r1.y;
  dst[(bq + 2) * HK + kb + 128] = r1.z;  dst[(bq + 3) * HK + kb + 128] = r1.w;
  dst[(bq + 0) * HK + kb + 256] = r2.x;  dst[(bq + 1) * HK + kb + 256] = r2.y;
  dst[(bq + 2) * HK + kb + 256] = r2.z;  dst[(bq + 3) * HK + kb + 256] = r2.w;
  dst[(bq + 0) * HK + kb + 384] = r3.x;  dst[(bq + 1) * HK + kb + 384] = r3.y;
  dst[(bq + 2) * HK + kb + 384] = r3.z;  dst[(bq + 3) * HK + kb + 384] = r3.w;
}

// x tile: x[b][t][f] (read-only, plain cached) -> LDS [16b][EK]
__device__ __forceinline__ void stage_x(float* __restrict__ dst,
                                        const float* __restrict__ x, int t,
                                        int b0, int tid) {
  const int bb = tid >> 5;            // 0..15
  const int fq = (tid & 31) * 4;      // 0..124
  const float4 v =
      *(const float4*)(x + ((size_t)(b0 + bb) * SEQL + t) * FEAT + fq);
  *(float4*)(dst + bb * EK + fq) = v;
}

// ---- GEMV accumulate helpers (LDS b128 reads + float4 weight rows) --------
__device__ __forceinline__ void gemv512(float& a0, float& a1, float& a2,
                                        float& a3, const float* __restrict__ s,
                                        const float4* __restrict__ w0,
                                        const float4* __restrict__ w1,
                                        const float4* __restrict__ w2,
                                        const float4* __restrict__ w3) {
#pragma unroll 2
  for (int k4 = 0; k4 < 128; ++k4) {
    const float4 sv = *(const float4*)(s + k4 * 4);
    float4 w;
    w = w0[k4]; a0 += w.x * sv.x + w.y * sv.y + w.z * sv.z + w.w * sv.w;
    w = w1[k4]; a1 += w.x * sv.x + w.y * sv.y + w.z * sv.z + w.w * sv.w;
    w = w2[k4]; a2 += w.x * sv.x + w.y * sv.y + w.z * sv.z + w.w * sv.w;
    w = w3[k4]; a3 += w.x * sv.x + w.y * sv.y + w.z * sv.z + w.w * sv.w;
  }
}
__device__ __forceinline__ void gemv128(float& a0, float& a1, float& a2,
                                        float& a3, const float* __restrict__ s,
                                        const float4* __restrict__ w0,
                                        const float4* __restrict__ w1,
                                        const float4* __restrict__ w2,
                                        const float4* __restrict__ w3) {
#pragma unroll 4
  for (int k4 = 0; k4 < 32; ++k4) {
    const float4 sv = *(const float4*)(s + k4 * 4);
    float4 w;
    w = w0[k4]; a0 += w.x * sv.x + w.y * sv.y + w.z * sv.z + w.w * sv.w;
    w = w1[k4]; a1 += w.x * sv.x + w.y * sv.y + w.z * sv.z + w.w * sv.w;
    w = w2[k4]; a2 += w.x * sv.x + w.y * sv.y + w.z * sv.z + w.w * sv.w;
    w = w3[k4]; a3 += w.x * sv.x + w.y * sv.y + w.z * sv.z + w.w * sv.w;
  }
}

__device__ __forceinline__ void act_store(float a0, float a1, float a2,
                                          float a3, float& c_reg,
                                          float* __restrict__ HoutT,
                                          size_t cit) {
  const float ig = sigf_(a0), fg = sigf_(a1);
  const float gg = tanh_(a2), og = sigf_(a3);
  const float cn = fg * c_reg + ig * gg;
  c_reg = cn;
  stg_sc(HoutT + cit, og * tanh_(cn));
}

// ---------------------------------------------------------------------------
// Persistent kernel: 256 WGs x 512 threads, 82.9KB LDS -> exactly 1 WG/CU.
// ---------------------------------------------------------------------------
__global__ __launch_bounds__(512, 2) void k_persist(
    const float* __restrict__ x,
    const float* __restrict__ enc_w, const float* __restrict__ enc_b,
    const float* __restrict__ wih0, const float* __restrict__ whh0,
    const float* __restrict__ bih0, const float* __restrict__ bhh0,
    const float* __restrict__ wih1, const float* __restrict__ whh1,
    const float* __restrict__ bih1, const float* __restrict__ bhh1,
    const float* __restrict__ dec_w, const float* __restrict__ dec_b,
    const float* __restrict__ Wcomp, const float* __restrict__ bcomp,
    float* __restrict__ h0A, float* __restrict__ h0B,
    float* __restrict__ h1A, float* __restrict__ h1B,
    int* __restrict__ bar, float* __restrict__ out) {
  __shared__ float s_h0[16 * HK];
  __shared__ float s_h1[16 * HK];
  __shared__ float s_x[16 * EK];
  __shared__ float s_e[16 * EK];

  const int wg = blockIdx.x;
  const int tid = threadIdx.x;
  const int ut = (wg & 7) * 4 + ((wg >> 3) & 3);  // XCD-affine unit tile
  const int bt = wg >> 5;                          // barrier group
  const int b0 = bt * 16;
  const int half = tid >> 8;
  const int t8 = tid & 255;
  const int u = t8 >> 4, b = t8 & 15;
  const int ug = ut * 16 + u;
  const size_t cit = (size_t)ug * 128 + b0 + b;   // transposed h index

  float* h0b[2] = {h0A, h0B};
  float* h1b[2] = {h1A, h1B};
  const float* sh0row = s_h0 + b * HK;
  const float* sh1row = s_h1 + b * HK;
  const float* serow  = s_e + b * EK;

  // hoisted weight-row pointers (VGPR-resident for all 639 steps)
  const float4* e0p = (const float4*)(wih0 + (size_t)ug * FEAT);
  const float4* e1p = (const float4*)(wih0 + (size_t)(512 + ug) * FEAT);
  const float4* e2p = (const float4*)(wih0 + (size_t)(1024 + ug) * FEAT);
  const float4* e3p = (const float4*)(wih0 + (size_t)(1536 + ug) * FEAT);
  const float4* H00 = (const float4*)(whh0 + (size_t)ug * HID);
  const float4* H01 = (const float4*)(whh0 + (size_t)(512 + ug) * HID);
  const float4* H02 = (const float4*)(whh0 + (size_t)(1024 + ug) * HID);
  const float4* H03 = (const float4*)(whh0 + (size_t)(1536 + ug) * HID);
  const float4* Wc0 = (const float4*)(Wcomp + (size_t)ug * HID);
  const float4* Wc1 = (const float4*)(Wcomp + (size_t)(512 + ug) * HID);
  const float4* Wc2 = (const float4*)(Wcomp + (size_t)(1024 + ug) * HID);
  const float4* Wc3 = (const float4*)(Wcomp + (size_t)(1536 + ug) * HID);
  const float4* I10 = (const float4*)(wih1 + (size_t)ug * HID);
  const float4* I11 = (const float4*)(wih1 + (size_t)(512 + ug) * HID);
  const float4* I12 = (const float4*)(wih1 + (size_t)(1024 + ug) * HID);
  const float4* I13 = (const float4*)(wih1 + (size_t)(1536 + ug) * HID);
  const float4* H10 = (const float4*)(whh1 + (size_t)ug * HID);
  const float4* H11 = (const float4*)(whh1 + (size_t)(512 + ug) * HID);
  const float4* H12 = (const float4*)(whh1 + (size_t)(1024 + ug) * HID);
  const float4* H13 = (const float4*)(whh1 + (size_t)(1536 + ug) * HID);
  const float bt00 = bih0[ug] + bhh0[ug];
  const float bt01 = bih0[512 + ug] + bhh0[512 + ug];
  const float bt02 = bih0[1024 + ug] + bhh0[1024 + ug];
  const float bt03 = bih0[1536 + ug] + bhh0[1536 + ug];
  const float ba00 = bt00 + bcomp[ug];
  const float ba01 = bt01 + bcomp[512 + ug];
  const float ba02 = bt02 + bcomp[1024 + ug];
  const float ba03 = bt03 + bcomp[1536 + ug];
  const float b10 = bih1[ug] + bhh1[ug];
  const float b11 = bih1[512 + ug] + bhh1[512 + ug];
  const float b12 = bih1[1024 + ug] + bhh1[1024 + ug];
  const float b13 = bih1[1536 + ug] + bhh1[1536 + ug];

  // encoder role (all 512 threads): 4 f-outputs for one b
  const int eb = tid & 15;
  const int f0 = (tid >> 4) * 4;                 // 0..124
  const float4* ew0 = (const float4*)(enc_w + (size_t)f0 * FEAT);
  const float4* ew1 = (const float4*)(enc_w + (size_t)(f0 + 1) * FEAT);
  const float4* ew2 = (const float4*)(enc_w + (size_t)(f0 + 2) * FEAT);
  const float4* ew3 = (const float4*)(enc_w + (size_t)(f0 + 3) * FEAT);
  const float encb0 = enc_b[f0], encb1 = enc_b[f0 + 1];
  const float encb2 = enc_b[f0 + 2], encb3 = enc_b[f0 + 3];
  const float* sxrow = s_x + eb * EK;

  // decoder role
  const int is_dec = (half == 1) && (((wg >> 3) & 3) == 0);
  const int jdec = (wg & 7) * 16 + (t8 >> 4);
  const int bd = t8 & 15;
  const float4* decr = (const float4*)(dec_w + (size_t)jdec * HID);
  const float decb = dec_b[jdec];

  float c_reg = 0.0f;
  int ph = 0;
  bool last = false;

  // ---- teacher-forced phase: tick t = LSTM0(t) || LSTM1(t-1) --------------
  stage_x(s_x, x, 0, b0, tid);
  for (int t = 0; t < SEQL; ++t) {
    const float* h0in = h0b[(t + 1) & 1];
    float* h0out = h0b[t & 1];
    const float* h1in = h1b[t & 1];
    float* h1out = h1b[(t + 1) & 1];

    stage_h(s_h0, h0in, b0, tid);
    stage_h(s_h1, h1in, b0, tid);
    __syncthreads();

    {  // cooperative encoder: e(t) = x_t @ enc_w^T + enc_b
      float a0 = encb0, a1 = encb1, a2 = encb2, a3 = encb3;
      gemv128(a0, a1, a2, a3, sxrow, ew0, ew1, ew2, ew3);
      *(float4*)(s_e + eb * EK + f0) = make_float4(a0, a1, a2, a3);
    }
    __syncthreads();

    if (half == 0) {
      float a0 = bt00, a1 = bt01, a2 = bt02, a3 = bt03;
      gemv512(a0, a1, a2, a3, sh0row, H00, H01, H02, H03);
      gemv128(a0, a1, a2, a3, serow, e0p, e1p, e2p, e3p);
      act_store(a0, a1, a2, a3, c_reg, h0out, cit);
    } else if (t > 0) {
      float a0 = b10, a1 = b11, a2 = b12, a3 = b13;
      gemv512(a0, a1, a2, a3, sh0row, I10, I11, I12, I13);  // A = h0(t-1)
      gemv512(a0, a1, a2, a3, sh1row, H10, H11, H12, H13);  // Hin = h1(t-2)
      act_store(a0, a1, a2, a3, c_reg, h1out, cit);
    }
    bar_arrive(bar, bt, ++ph, tid, last);
    if (t + 1 < SEQL) stage_x(s_x, x, t + 1, b0, tid);  // overlap poll
    bar_wait(bar, bt, ph, tid, last);
  }

  // ---- LSTM1(511): A = h0(511)=h0b[1], Hin = h1(510)=h1b[0] ---------------
  stage_h(s_h0, h0b[1], b0, tid);
  stage_h(s_h1, h1b[0], b0, tid);
  __syncthreads();
  if (half == 1) {
    float a0 = b10, a1 = b11, a2 = b12, a3 = b13;
    gemv512(a0, a1, a2, a3, sh0row, I10, I11, I12, I13);
    gemv512(a0, a1, a2, a3, sh1row, H10, H11, H12, H13);
    act_store(a0, a1, a2, a3, c_reg, h1b[1], cit);
  }
  bar_arrive(bar, bt, ++ph, tid, last);
  bar_wait(bar, bt, ph, tid, last);

  // ---- autoregressive phase ----------------------------------------------
  for (int t = SEQL; t < SEQL + PREDL - 1; ++t) {
    const float* h1prev = h1b[(t + 1) & 1];
    const float* h0prev = h0b[(t + 1) & 1];
    float* h0cur = h0b[t & 1];
    float* h1cur = h1b[t & 1];

    // phase 1: LSTM0-AR(t) (half 0) + decode h1(t-1) (64 dec WGs)
    stage_h(s_h1, h1prev, b0, tid);
    stage_h(s_h0, h0prev, b0, tid);
    __syncthreads();
    if (half == 0) {
      float a0 = ba00, a1 = ba01, a2 = ba02, a3 = ba03;
      gemv512(a0, a1, a2, a3, sh1row, Wc0, Wc1, Wc2, Wc3);
      gemv512(a0, a1, a2, a3, sh0row, H00, H01, H02, H03);
      act_store(a0, a1, a2, a3, c_reg, h0cur, cit);
    } else if (is_dec) {
      float acc = decb;
      const float* srow = s_h1 + bd * HK;
#pragma unroll 2
      for (int k4 = 0; k4 < 128; ++k4) {
        const float4 sv = *(const float4*)(srow + k4 * 4);
        const float4 w = decr[k4];
        acc += w.x * sv.x + w.y * sv.y + w.z * sv.z + w.w * sv.w;
      }
      out[((size_t)(b0 + bd) * PREDL + (t - SEQL)) * FEAT + jdec] = acc;
    }
    bar_arrive(bar, bt, ++ph, tid, last);
    bar_wait(bar, bt, ph, tid, last);

    // phase 2: LSTM1(t): A = h0(t), Hin = h1(t-1) (still staged in s_h1)
    stage_h(s_h0, h0cur, b0, tid);
    __syncthreads();
    if (half == 1) {
      float a0 = b10, a1 = b11, a2 = b12, a3 = b13;
      gemv512(a0, a1, a2, a3, sh0row, I10, I11, I12, I13);
      gemv512(a0, a1, a2, a3, sh1row, H10, H11, H12, H13);
      act_store(a0, a1, a2, a3, c_reg, h1cur, cit);
    }
    bar_arrive(bar, bt, ++ph, tid, last);
    bar_wait(bar, bt, ph, tid, last);
  }

  // ---- final output: decode h1(638) = h1b[0], step 127 --------------------
  stage_h(s_h1, h1b[0], b0, tid);
  __syncthreads();
  if (is_dec) {
    float acc = decb;
    const float* srow = s_h1 + bd * HK;
#pragma unroll 2
    for (int k4 = 0; k4 < 128; ++k4) {
      const float4 sv = *(const float4*)(srow + k4 * 4);
      const float4 w = decr[k4];
      acc += w.x * sv.x + w.y * sv.y + w.z * sv.z + w.w * sv.w;
    }
    out[((size_t)(b0 + bd) * PREDL + (PREDL - 1)) * FEAT + jdec] = acc;
  }
}

// ----- prologue: composite weight/bias (verified round 0/1) ----------------
__global__ void k_b1(const float* __restrict__ enc_w,
                     const float* __restrict__ dec_w, float* __restrict__ B1) {
  const int idx = blockIdx.x * 256 + threadIdx.x;
  const int j = idx >> 9, m = idx & 511;
  float acc = 0.0f;
  for (int k = 0; k < FEAT; ++k) acc += enc_w[j * FEAT + k] * dec_w[k * HID + m];
  B1[idx] = acc;
}
__global__ void k_wcomp(const float* __restrict__ wih0,
                        const float* __restrict__ B1, float* __restrict__ W) {
  const size_t idx = (size_t)blockIdx.x * 256 + threadIdx.x;
  const int n = (int)(idx >> 9), m = (int)(idx & 511);
  float acc = 0.0f;
  for (int k = 0; k < FEAT; ++k) acc += wih0[n * FEAT + k] * B1[k * HID + m];
  W[idx] = acc;
}
__global__ void k_te(const float* __restrict__ enc_w,
                     const float* __restrict__ enc_b,
                     const float* __restrict__ dec_b, float* __restrict__ te) {
  const int j = threadIdx.x;
  float acc = enc_b[j];
  for (int k = 0; k < FEAT; ++k) acc += dec_b[k] * enc_w[j * FEAT + k];
  te[j] = acc;
}
__global__ void k_bcomp(const float* __restrict__ wih0,
                        const float* __restrict__ te, float* __restrict__ bc) {
  const int n = blockIdx.x * 256 + threadIdx.x;
  float acc = 0.0f;
  for (int j = 0; j < FEAT; ++j) acc += wih0[n * FEAT + j] * te[j];
  bc[n] = acc;
}

// ---------------------------------------------------------------------------
extern "C" void kernel_launch(void* const* d_in, const int* in_sizes, int n_in,
                              void* d_out, int out_size, void* d_ws,
                              size_t ws_size, hipStream_t stream) {
  const float* x     = (const float*)d_in[0];
  const float* enc_w = (const float*)d_in[1];
  const float* enc_b = (const float*)d_in[2];
  const float* dec_w = (const float*)d_in[3];
  const float* dec_b = (const float*)d_in[4];
  const float* wih0  = (const float*)d_in[5];
  const float* whh0  = (const float*)d_in[6];
  const float* bih0  = (const float*)d_in[7];
  const float* bhh0  = (const float*)d_in[8];
  const float* wih1  = (const float*)d_in[9];
  const float* whh1  = (const float*)d_in[10];
  const float* bih1  = (const float*)d_in[11];
  const float* bhh1  = (const float*)d_in[12];
  float* out = (float*)d_out;

  float* ws = (float*)d_ws;
  float* h0A   = ws;                     // [512][128] transposed
  float* h0B   = ws + 65536;
  float* h1A   = ws + 131072;
  float* h1B   = ws + 196608;
  int*   bar   = (int*)(ws + 262144);    // 1024 ints
  float* Wcomp = ws + 263168;            // 2048*512
  float* B1    = ws + 1311744;           // 128*512
  float* te    = ws + 1377280;           // 128
  float* bcomp = ws + 1377408;           // 2048

  // zero h states + barrier counters each launch (graph replays rerun this)
  hipMemsetAsync(ws, 0, (size_t)263168 * sizeof(float) + 4096, stream);

  k_b1<<<256, 256, 0, stream>>>(enc_w, dec_w, B1);
  k_wcomp<<<4096, 256, 0, stream>>>(wih0, B1, Wcomp);
  k_te<<<1, 128, 0, stream>>>(enc_w, enc_b, dec_b, te);
  k_bcomp<<<8, 256, 0, stream>>>(wih0, te, bcomp);

  k_persist<<<NWG, 512, 0, stream>>>(
      x, enc_w, enc_b, wih0, whh0, bih0, bhh0, wih1, whh1, bih1, bhh1,
      dec_w, dec_b, Wcomp, bcomp, h0A, h0B, h1A, h1B, bar, out);
}

// Round 4
// 37384.592 us; speedup vs baseline: 1.6939x; 1.0272x over previous
//
#include <hip/hip_runtime.h>
#include <math.h>

#define HID 512
#define FEAT 128
#define SEQL 512
#define PREDL 128
#define NWG 256
#define HK 516   // LDS row stride (floats) for h tiles
#define EK 132   // LDS row stride for x/e tiles

typedef float v2f __attribute__((ext_vector_type(2)));

__device__ __forceinline__ float sigf_(float x) { return 1.0f / (1.0f + __expf(-x)); }
__device__ __forceinline__ float tanh_(float x) {
  float ax = fabsf(x);
  float e2 = __expf(-2.0f * ax);
  return copysignf((1.0f - e2) / (1.0f + e2), x);
}

__device__ __forceinline__ void stg_sc(float* p, float v) {
  __hip_atomic_store(p, v, __ATOMIC_RELAXED, __HIP_MEMORY_SCOPE_AGENT);
}

// bt-local barrier (32 WGs/group), relaxed agent atomics only (round-3 verified)
__device__ __forceinline__ void bar_arrive(int* __restrict__ bar, int grp,
                                           int phase, int tid, bool& last) {
  __syncthreads();
  if (tid == 0) {
    const int a = __hip_atomic_fetch_add(bar + grp * 32, 1, __ATOMIC_RELAXED,
                                         __HIP_MEMORY_SCOPE_AGENT);
    last = (a == 32 * phase - 1);
    if (last)
      __hip_atomic_store(bar + 512 + grp * 32, phase, __ATOMIC_RELAXED,
                         __HIP_MEMORY_SCOPE_AGENT);
  }
  asm volatile("" ::: "memory");
}
__device__ __forceinline__ void bar_wait(int* __restrict__ bar, int grp,
                                         int phase, int tid, bool last) {
  asm volatile("" ::: "memory");
  if (tid == 0 && !last) {
    while (__hip_atomic_load(bar + 512 + grp * 32, __ATOMIC_RELAXED,
                             __HIP_MEMORY_SCOPE_AGENT) < phase)
      __builtin_amdgcn_s_sleep(1);
  }
  __syncthreads();
}

// ---- staging: coherent sc0/sc1 dwordx4 loads, LDS transpose scatter --------
__device__ __forceinline__ void stage_h2(float* __restrict__ dA,
                                         const float* __restrict__ sA,
                                         float* __restrict__ dB,
                                         const float* __restrict__ sB,
                                         int b0, int tid) {
  const int kb = tid >> 2;
  const int bq = (tid & 3) * 4;
  const float* a0 = sA + (size_t)kb * 128 + b0 + bq;
  const float* a1 = sA + ((size_t)kb + 128) * 128 + b0 + bq;
  const float* a2 = sA + ((size_t)kb + 256) * 128 + b0 + bq;
  const float* a3 = sA + ((size_t)kb + 384) * 128 + b0 + bq;
  const float* c0 = sB + (size_t)kb * 128 + b0 + bq;
  const float* c1 = sB + ((size_t)kb + 128) * 128 + b0 + bq;
  const float* c2 = sB + ((size_t)kb + 256) * 128 + b0 + bq;
  const float* c3 = sB + ((size_t)kb + 384) * 128 + b0 + bq;
  float4 r0, r1, r2, r3, q0, q1, q2, q3;
  asm volatile(
      "global_load_dwordx4 %0, %8, off sc0 sc1\n\t"
      "global_load_dwordx4 %1, %9, off sc0 sc1\n\t"
      "global_load_dwordx4 %2, %10, off sc0 sc1\n\t"
      "global_load_dwordx4 %3, %11, off sc0 sc1\n\t"
      "global_load_dwordx4 %4, %12, off sc0 sc1\n\t"
      "global_load_dwordx4 %5, %13, off sc0 sc1\n\t"
      "global_load_dwordx4 %6, %14, off sc0 sc1\n\t"
      "global_load_dwordx4 %7, %15, off sc0 sc1\n\t"
      "s_waitcnt vmcnt(0)"
      : "=&v"(r0), "=&v"(r1), "=&v"(r2), "=&v"(r3),
        "=&v"(q0), "=&v"(q1), "=&v"(q2), "=&v"(q3)
      : "v"(a0), "v"(a1), "v"(a2), "v"(a3),
        "v"(c0), "v"(c1), "v"(c2), "v"(c3)
      : "memory");
  dA[(bq + 0) * HK + kb] = r0.x; dA[(bq + 1) * HK + kb] = r0.y;
  dA[(bq + 2) * HK + kb] = r0.z; dA[(bq + 3) * HK + kb] = r0.w;
  dA[(bq + 0) * HK + kb + 128] = r1.x; dA[(bq + 1) * HK + kb + 128] = r1.y;
  dA[(bq + 2) * HK + kb + 128] = r1.z; dA[(bq + 3) * HK + kb + 128] = r1.w;
  dA[(bq + 0) * HK + kb + 256] = r2.x; dA[(bq + 1) * HK + kb + 256] = r2.y;
  dA[(bq + 2) * HK + kb + 256] = r2.z; dA[(bq + 3) * HK + kb + 256] = r2.w;
  dA[(bq + 0) * HK + kb + 384] = r3.x; dA[(bq + 1) * HK + kb + 384] = r3.y;
  dA[(bq + 2) * HK + kb + 384] = r3.z; dA[(bq + 3) * HK + kb + 384] = r3.w;
  dB[(bq + 0) * HK + kb] = q0.x; dB[(bq + 1) * HK + kb] = q0.y;
  dB[(bq + 2) * HK + kb] = q0.z; dB[(bq + 3) * HK + kb] = q0.w;
  dB[(bq + 0) * HK + kb + 128] = q1.x; dB[(bq + 1) * HK + kb + 128] = q1.y;
  dB[(bq + 2) * HK + kb + 128] = q1.z; dB[(bq + 3) * HK + kb + 128] = q1.w;
  dB[(bq + 0) * HK + kb + 256] = q2.x; dB[(bq + 1) * HK + kb + 256] = q2.y;
  dB[(bq + 2) * HK + kb + 256] = q2.z; dB[(bq + 3) * HK + kb + 256] = q2.w;
  dB[(bq + 0) * HK + kb + 384] = q3.x; dB[(bq + 1) * HK + kb + 384] = q3.y;
  dB[(bq + 2) * HK + kb + 384] = q3.z; dB[(bq + 3) * HK + kb + 384] = q3.w;
}
__device__ __forceinline__ void stage_h1t(float* __restrict__ dst,
                                          const float* __restrict__ src,
                                          int b0, int tid) {
  const int kb = tid >> 2;
  const int bq = (tid & 3) * 4;
  const float* p0 = src + (size_t)kb * 128 + b0 + bq;
  const float* p1 = src + ((size_t)kb + 128) * 128 + b0 + bq;
  const float* p2 = src + ((size_t)kb + 256) * 128 + b0 + bq;
  const float* p3 = src + ((size_t)kb + 384) * 128 + b0 + bq;
  float4 r0, r1, r2, r3;
  asm volatile(
      "global_load_dwordx4 %0, %4, off sc0 sc1\n\t"
      "global_load_dwordx4 %1, %5, off sc0 sc1\n\t"
      "global_load_dwordx4 %2, %6, off sc0 sc1\n\t"
      "global_load_dwordx4 %3, %7, off sc0 sc1\n\t"
      "s_waitcnt vmcnt(0)"
      : "=&v"(r0), "=&v"(r1), "=&v"(r2), "=&v"(r3)
      : "v"(p0), "v"(p1), "v"(p2), "v"(p3)
      : "memory");
  dst[(bq + 0) * HK + kb] = r0.x; dst[(bq + 1) * HK + kb] = r0.y;
  dst[(bq + 2) * HK + kb] = r0.z; dst[(bq + 3) * HK + kb] = r0.w;
  dst[(bq + 0) * HK + kb + 128] = r1.x; dst[(bq + 1) * HK + kb + 128] = r1.y;
  dst[(bq + 2) * HK + kb + 128] = r1.z; dst[(bq + 3) * HK + kb + 128] = r1.w;
  dst[(bq + 0) * HK + kb + 256] = r2.x; dst[(bq + 1) * HK + kb + 256] = r2.y;
  dst[(bq + 2) * HK + kb + 256] = r2.z; dst[(bq + 3) * HK + kb + 256] = r2.w;
  dst[(bq + 0) * HK + kb + 384] = r3.x; dst[(bq + 1) * HK + kb + 384] = r3.y;
  dst[(bq + 2) * HK + kb + 384] = r3.z; dst[(bq + 3) * HK + kb + 384] = r3.w;
}
__device__ __forceinline__ void stage_x(float* __restrict__ dst,
                                        const float* __restrict__ x, int t,
                                        int b0, int tid) {
  const int bb = tid >> 5;
  const int fq = (tid & 31) * 4;
  const float4 v =
      *(const float4*)(x + ((size_t)(b0 + bb) * SEQL + t) * FEAT + fq);
  *(float4*)(dst + bb * EK + fq) = v;
}

// ---- packed-FMA GEMV primitives ------------------------------------------
__device__ __forceinline__ void pkf(v2f& a01, v2f& a23, float4 w, float h) {
  v2f hh; hh[0] = h; hh[1] = h;
  v2f lo; lo[0] = w.x; lo[1] = w.y;
  v2f hi; hi[0] = w.z; hi[1] = w.w;
  a01 = __builtin_elementwise_fma(lo, hh, a01);
  a23 = __builtin_elementwise_fma(hi, hh, a23);
}
// dual-matrix fused stream: W8[(u*512+k)*2 + {0:A,1:B}] (float4 units)
__device__ __forceinline__ void gemv_fused8(v2f& a01, v2f& a23,
                                            const float4* __restrict__ W8,
                                            size_t base,
                                            const float* __restrict__ rA,
                                            const float* __restrict__ rB,
                                            int k4b, int k4e) {
#pragma unroll 2
  for (int k4 = k4b; k4 < k4e; ++k4) {
    const float4 hA = *(const float4*)(rA + k4 * 4);
    const float4 hB = *(const float4*)(rB + k4 * 4);
    const size_t o = base + (size_t)k4 * 8;
    pkf(a01, a23, W8[o + 0], hA.x); pkf(a01, a23, W8[o + 1], hB.x);
    pkf(a01, a23, W8[o + 2], hA.y); pkf(a01, a23, W8[o + 3], hB.y);
    pkf(a01, a23, W8[o + 4], hA.z); pkf(a01, a23, W8[o + 5], hB.z);
    pkf(a01, a23, W8[o + 6], hA.w); pkf(a01, a23, W8[o + 7], hB.w);
  }
}
// one half of a dual stream (sel=1 -> B half)
__device__ __forceinline__ void gemv_half8(v2f& a01, v2f& a23,
                                           const float4* __restrict__ W8,
                                           size_t base, int sel,
                                           const float* __restrict__ row,
                                           int nk4) {
#pragma unroll 4
  for (int k4 = 0; k4 < nk4; ++k4) {
    const float4 h = *(const float4*)(row + k4 * 4);
    const size_t o = base + (size_t)k4 * 8 + sel;
    pkf(a01, a23, W8[o + 0], h.x);
    pkf(a01, a23, W8[o + 2], h.y);
    pkf(a01, a23, W8[o + 4], h.z);
    pkf(a01, a23, W8[o + 6], h.w);
  }
}
// plain 4-interleaved stream: W4[u*K + k] (float4 units)
__device__ __forceinline__ void gemv_p4(v2f& a01, v2f& a23,
                                        const float4* __restrict__ W4,
                                        size_t base,
                                        const float* __restrict__ row,
                                        int nk4) {
#pragma unroll 4
  for (int k4 = 0; k4 < nk4; ++k4) {
    const float4 h = *(const float4*)(row + k4 * 4);
    const size_t o = base + (size_t)k4 * 4;
    pkf(a01, a23, W4[o + 0], h.x);
    pkf(a01, a23, W4[o + 1], h.y);
    pkf(a01, a23, W4[o + 2], h.z);
    pkf(a01, a23, W4[o + 3], h.w);
  }
}

__device__ __forceinline__ void act_store(v2f a01, v2f a23, float& c_reg,
                                          float* __restrict__ HoutT,
                                          size_t cit) {
  const float ig = sigf_(a01[0]), fg = sigf_(a01[1]);
  const float gg = tanh_(a23[0]), og = sigf_(a23[1]);
  const float cn = fg * c_reg + ig * gg;
  c_reg = cn;
  stg_sc(HoutT + cit, og * tanh_(cn));
}

// ---------------------------------------------------------------------------
__global__ __launch_bounds__(512, 1) void k_persist(
    const float* __restrict__ x,
    const float* __restrict__ enc4, const float* __restrict__ enc_b,
    const float* __restrict__ wih04, const float* __restrict__ Wa8,
    const float* __restrict__ Wf8,
    const float* __restrict__ bih0, const float* __restrict__ bhh0,
    const float* __restrict__ bih1, const float* __restrict__ bhh1,
    const float* __restrict__ dec_w, const float* __restrict__ dec_b,
    const float* __restrict__ bcomp,
    float* __restrict__ h0A, float* __restrict__ h0B,
    float* __restrict__ h1A, float* __restrict__ h1B,
    int* __restrict__ bar, float* __restrict__ out) {
  __shared__ float s_h0[16 * HK];
  __shared__ float s_h1[16 * HK];
  __shared__ float s_x[16 * EK];
  __shared__ float s_e[16 * EK];
  __shared__ float s_red[1536];

  const int wg = blockIdx.x;
  const int tid = threadIdx.x;
  const int ut = (wg & 7) * 4 + ((wg >> 3) & 3);
  const int bt = wg >> 5;
  const int b0 = bt * 16;
  const int t8 = tid & 255;
  const int u = t8 >> 4, b = t8 & 15;
  const int ug = ut * 16 + u;
  const size_t cit = (size_t)ug * 128 + b0 + b;

  float* h0b[2] = {h0A, h0B};
  float* h1b[2] = {h1A, h1B};
  const float* sh0row = s_h0 + b * HK;
  const float* sh1row = s_h1 + b * HK;
  const float* serow = s_e + b * EK;

  const float4* W8a = (const float4*)Wa8;   // [Wcomp | whh0]
  const float4* W8f = (const float4*)Wf8;   // [wih1 | whh1]
  const float4* W4i = (const float4*)wih04;
  const float4* W4e = (const float4*)enc4;
  const size_t baseG = (size_t)ug * 1024;   // f4 base of dual streams
  const size_t baseI = (size_t)ug * 128;    // wih0_4

  const float bt00 = bih0[ug] + bhh0[ug];
  const float bt01 = bih0[512 + ug] + bhh0[512 + ug];
  const float bt02 = bih0[1024 + ug] + bhh0[1024 + ug];
  const float bt03 = bih0[1536 + ug] + bhh0[1536 + ug];
  const float ba00 = bt00 + bcomp[ug];
  const float ba01 = bt01 + bcomp[512 + ug];
  const float ba02 = bt02 + bcomp[1024 + ug];
  const float ba03 = bt03 + bcomp[1536 + ug];
  const float b10 = bih1[ug] + bhh1[ug];
  const float b11 = bih1[512 + ug] + bhh1[512 + ug];
  const float b12 = bih1[1024 + ug] + bhh1[1024 + ug];
  const float b13 = bih1[1536 + ug] + bhh1[1536 + ug];

  // encoder role constants (all 512 threads): 4 f-outputs for one batch
  const int eb = tid & 15;
  const int fb = tid >> 4;                  // 0..31
  const size_t baseE = (size_t)fb * 128;
  const float eb0 = enc_b[fb * 4], eb1 = enc_b[fb * 4 + 1];
  const float eb2 = enc_b[fb * 4 + 2], eb3 = enc_b[fb * 4 + 3];
  const float* sxrow = s_x + eb * EK;

  // decoder role constants (all WGs): 4 dec rows per WG
  const int djj = tid >> 7, dbb = (tid >> 3) & 15, dk8 = tid & 7;
  const int jd = (wg & 31) * 4 + djj;
  const float4* decr = (const float4*)(dec_w + (size_t)jd * HID);
  const float* dhrow = s_h1 + dbb * HK;

  float c_reg = 0.0f;
  int ph = 0;
  bool last = false;

  // ================= teacher-forced phase ==================================
  stage_x(s_x, x, 0, b0, tid);
  for (int t = 0; t < SEQL; ++t) {
    const float* h0in = h0b[(t + 1) & 1];
    float* h0out = h0b[t & 1];
    const float* h1in = h1b[t & 1];
    float* h1out = h1b[(t + 1) & 1];

    stage_h2(s_h0, h0in, s_h1, h1in, b0, tid);
    __syncthreads();

    {  // cooperative encoder
      v2f a01; a01[0] = eb0; a01[1] = eb1;
      v2f a23; a23[0] = eb2; a23[1] = eb3;
      gemv_p4(a01, a23, W4e, baseE, sxrow, 32);
      *(float4*)(s_e + eb * EK + fb * 4) =
          make_float4(a01[0], a01[1], a23[0], a23[1]);
    }
    __syncthreads();

    if (tid < 256) {  // LSTM0(t)
      v2f a01; a01[0] = bt00; a01[1] = bt01;
      v2f a23; a23[0] = bt02; a23[1] = bt03;
      gemv_half8(a01, a23, W8a, baseG, 1, sh0row, 128);  // whh0 @ h0(t-1)
      gemv_p4(a01, a23, W4i, baseI, serow, 32);          // wih0 @ e(t)
      act_store(a01, a23, c_reg, h0out, cit);
    } else if (t > 0) {  // LSTM1(t-1)
      v2f a01; a01[0] = b10; a01[1] = b11;
      v2f a23; a23[0] = b12; a23[1] = b13;
      gemv_fused8(a01, a23, W8f, baseG, sh0row, sh1row, 0, 128);
      act_store(a01, a23, c_reg, h1out, cit);
    }
    bar_arrive(bar, bt, ++ph, tid, last);
    if (t + 1 < SEQL) stage_x(s_x, x, t + 1, b0, tid);
    bar_wait(bar, bt, ph, tid, last);
  }

  // ================= LSTM1(511) (k-split across all threads) ==============
  stage_h2(s_h0, h0b[1], s_h1, h1b[0], b0, tid);
  __syncthreads();
  {
    const int own = (tid >= 256);
    v2f a01, a23;
    if (own) { a01[0] = b10; a01[1] = b11; a23[0] = b12; a23[1] = b13; }
    else { a01[0] = 0; a01[1] = 0; a23[0] = 0; a23[1] = 0; }
    const int kb4 = own ? 0 : 64;
    gemv_fused8(a01, a23, W8f, baseG, sh0row, sh1row, kb4, kb4 + 64);
    if (!own) {
      *(float4*)(s_red + t8 * 4) = make_float4(a01[0], a01[1], a23[0], a23[1]);
    }
    __syncthreads();
    if (own) {
      const float4 p = *(const float4*)(s_red + t8 * 4);
      a01[0] += p.x; a01[1] += p.y; a23[0] += p.z; a23[1] += p.w;
      act_store(a01, a23, c_reg, h1b[1], cit);
    }
  }
  bar_arrive(bar, bt, ++ph, tid, last);
  bar_wait(bar, bt, ph, tid, last);

  // ================= autoregressive phase ==================================
  for (int t = SEQL; t < SEQL + PREDL - 1; ++t) {
    const float* h1prev = h1b[(t + 1) & 1];
    const float* h0prev = h0b[(t + 1) & 1];
    float* h0cur = h0b[t & 1];
    float* h1cur = h1b[t & 1];

    // ---- phase 1: LSTM0-AR(t) k-split + decode h1(t-1) -------------------
    stage_h2(s_h1, h1prev, s_h0, h0prev, b0, tid);
    __syncthreads();
    {
      const int own = (tid < 256);
      v2f a01, a23;
      if (own) { a01[0] = ba00; a01[1] = ba01; a23[0] = ba02; a23[1] = ba03; }
      else { a01[0] = 0; a01[1] = 0; a23[0] = 0; a23[1] = 0; }
      const int kb4 = own ? 0 : 64;
      // A = h1prev @ Wcomp ; B = h0prev @ whh0
      gemv_fused8(a01, a23, W8a, baseG, sh1row, sh0row, kb4, kb4 + 64);
      // decode partial (all threads)
      float dacc = 0.0f;
#pragma unroll 4
      for (int k4 = dk8 * 16; k4 < dk8 * 16 + 16; ++k4) {
        const float4 w = decr[k4];
        const float4 h = *(const float4*)(dhrow + k4 * 4);
        dacc += w.x * h.x + w.y * h.y + w.z * h.z + w.w * h.w;
      }
      s_red[1024 + tid] = dacc;
      if (!own)
        *(float4*)(s_red + t8 * 4) = make_float4(a01[0], a01[1], a23[0], a23[1]);
      __syncthreads();
      if (own) {
        const float4 p = *(const float4*)(s_red + t8 * 4);
        a01[0] += p.x; a01[1] += p.y; a23[0] += p.z; a23[1] += p.w;
        act_store(a01, a23, c_reg, h0cur, cit);
      }
      if (dk8 == 0) {
        float s = dec_b[jd];
#pragma unroll
        for (int i = 0; i < 8; ++i) s += s_red[1024 + tid + i];
        out[((size_t)(b0 + dbb) * PREDL + (t - SEQL)) * FEAT + jd] = s;
      }
    }
    bar_arrive(bar, bt, ++ph, tid, last);
    bar_wait(bar, bt, ph, tid, last);

    // ---- phase 2: LSTM1(t) k-split ---------------------------------------
    stage_h1t(s_h0, h0cur, b0, tid);
    __syncthreads();
    {
      const int own = (tid >= 256);
      v2f a01, a23;
      if (own) { a01[0] = b10; a01[1] = b11; a23[0] = b12; a23[1] = b13; }
      else { a01[0] = 0; a01[1] = 0; a23[0] = 0; a23[1] = 0; }
      const int kb4 = own ? 0 : 64;
      // A = h0(t) @ wih1 ; B = h1(t-1) (still in s_h1) @ whh1
      gemv_fused8(a01, a23, W8f, baseG, sh0row, sh1row, kb4, kb4 + 64);
      if (!own)
        *(float4*)(s_red + t8 * 4) = make_float4(a01[0], a01[1], a23[0], a23[1]);
      __syncthreads();
      if (own) {
        const float4 p = *(const float4*)(s_red + t8 * 4);
        a01[0] += p.x; a01[1] += p.y; a23[0] += p.z; a23[1] += p.w;
        act_store(a01, a23, c_reg, h1cur, cit);
      }
    }
    bar_arrive(bar, bt, ++ph, tid, last);
    bar_wait(bar, bt, ph, tid, last);
  }

  // ================= final output: decode h1(638) ==========================
  stage_h1t(s_h1, h1b[0], b0, tid);
  __syncthreads();
  {
    float dacc = 0.0f;
#pragma unroll 4
    for (int k4 = dk8 * 16; k4 < dk8 * 16 + 16; ++k4) {
      const float4 w = decr[k4];
      const float4 h = *(const float4*)(dhrow + k4 * 4);
      dacc += w.x * h.x + w.y * h.y + w.z * h.z + w.w * h.w;
    }
    s_red[1024 + tid] = dacc;
    __syncthreads();
    if (dk8 == 0) {
      float s = dec_b[jd];
#pragma unroll
      for (int i = 0; i < 8; ++i) s += s_red[1024 + tid + i];
      out[((size_t)(b0 + dbb) * PREDL + (PREDL - 1)) * FEAT + jd] = s;
    }
  }
}

// ===== prologue ============================================================
__global__ void k_b1(const float* __restrict__ enc_w,
                     const float* __restrict__ dec_w, float* __restrict__ B1) {
  const int idx = blockIdx.x * 256 + threadIdx.x;
  const int j = idx >> 9, m = idx & 511;
  float acc = 0.0f;
  for (int k = 0; k < FEAT; ++k) acc += enc_w[j * FEAT + k] * dec_w[k * HID + m];
  B1[idx] = acc;
}
__global__ void k_te(const float* __restrict__ enc_w,
                     const float* __restrict__ enc_b,
                     const float* __restrict__ dec_b, float* __restrict__ te) {
  const int j = threadIdx.x;
  float acc = enc_b[j];
  for (int k = 0; k < FEAT; ++k) acc += dec_b[k] * enc_w[j * FEAT + k];
  te[j] = acc;
}
__global__ void k_bcomp(const float* __restrict__ wih0,
                        const float* __restrict__ te, float* __restrict__ bc) {
  const int n = blockIdx.x * 256 + threadIdx.x;
  float acc = 0.0f;
  for (int j = 0; j < FEAT; ++j) acc += wih0[n * FEAT + j] * te[j];
  bc[n] = acc;
}
// Wa8[(u*512+k)*8 + g] = Wcomp(g,u,k);  +4+g = whh0(g,u,k)
__global__ void k_wa8(const float* __restrict__ wih0,
                      const float* __restrict__ B1,
                      const float* __restrict__ whh0, float* __restrict__ W) {
  const int idx = blockIdx.x * 256 + threadIdx.x;
  const int uu = idx >> 9, k = idx & 511;
  float c[4];
#pragma unroll
  for (int g = 0; g < 4; ++g) {
    const float* wr = wih0 + ((size_t)(g * 512 + uu)) * FEAT;
    float acc = 0.0f;
    for (int j = 0; j < FEAT; ++j) acc += wr[j] * B1[j * HID + k];
    c[g] = acc;
  }
  float4* o = (float4*)(W + ((size_t)(uu * 512 + k)) * 8);
  o[0] = make_float4(c[0], c[1], c[2], c[3]);
  o[1] = make_float4(whh0[((size_t)uu) * 512 + k],
                     whh0[((size_t)(512 + uu)) * 512 + k],
                     whh0[((size_t)(1024 + uu)) * 512 + k],
                     whh0[((size_t)(1536 + uu)) * 512 + k]);
}
// Wf8[(u*512+k)*8 + g] = wih1(g,u,k);  +4+g = whh1(g,u,k)
__global__ void k_wf8(const float* __restrict__ wih1,
                      const float* __restrict__ whh1, float* __restrict__ W) {
  const int idx = blockIdx.x * 256 + threadIdx.x;
  const int uu = idx >> 9, k = idx & 511;
  float4* o = (float4*)(W + ((size_t)(uu * 512 + k)) * 8);
  o[0] = make_float4(wih1[((size_t)uu) * 512 + k],
                     wih1[((size_t)(512 + uu)) * 512 + k],
                     wih1[((size_t)(1024 + uu)) * 512 + k],
                     wih1[((size_t)(1536 + uu)) * 512 + k]);
  o[1] = make_float4(whh1[((size_t)uu) * 512 + k],
                     whh1[((size_t)(512 + uu)) * 512 + k],
                     whh1[((size_t)(1024 + uu)) * 512 + k],
                     whh1[((size_t)(1536 + uu)) * 512 + k]);
}
// wih04[(u*128+k)*4 + g] = wih0(g,u,k)
__global__ void k_wih04(const float* __restrict__ wih0, float* __restrict__ W) {
  const int idx = blockIdx.x * 256 + threadIdx.x;  // u(512) x k(128)
  const int uu = idx >> 7, k = idx & 127;
  float4* o = (float4*)(W + ((size_t)idx) * 4);
  o[0] = make_float4(wih0[((size_t)uu) * FEAT + k],
                     wih0[((size_t)(512 + uu)) * FEAT + k],
                     wih0[((size_t)(1024 + uu)) * FEAT + k],
                     wih0[((size_t)(1536 + uu)) * FEAT + k]);
}
// enc4[(fb*128+k)*4 + j] = enc_w[(fb*4+j)][k]
__global__ void k_enc4(const float* __restrict__ enc_w, float* __restrict__ W) {
  const int idx = blockIdx.x * 256 + threadIdx.x;  // fb(32) x k(128)
  const int fb = idx >> 7, k = idx & 127;
  float4* o = (float4*)(W + ((size_t)idx) * 4);
  o[0] = make_float4(enc_w[((size_t)(fb * 4 + 0)) * FEAT + k],
                     enc_w[((size_t)(fb * 4 + 1)) * FEAT + k],
                     enc_w[((size_t)(fb * 4 + 2)) * FEAT + k],
                     enc_w[((size_t)(fb * 4 + 3)) * FEAT + k]);
}

// ===== ws layout (floats) ==================================================
#define WS_H0A 0
#define WS_H0B 65536
#define WS_H1A 131072
#define WS_H1B 196608
#define WS_BAR 262144
#define WS_B1 263168
#define WS_TE 328704
#define WS_BCOMP 328832
#define WS_WIH04 330880
#define WS_ENC4 593024
#define WS_WA8 609408
#define WS_WF8 2706560

extern "C" void kernel_launch(void* const* d_in, const int* in_sizes, int n_in,
                              void* d_out, int out_size, void* d_ws,
                              size_t ws_size, hipStream_t stream) {
  const float* x     = (const float*)d_in[0];
  const float* enc_w = (const float*)d_in[1];
  const float* enc_b = (const float*)d_in[2];
  const float* dec_w = (const float*)d_in[3];
  const float* dec_b = (const float*)d_in[4];
  const float* wih0  = (const float*)d_in[5];
  const float* whh0  = (const float*)d_in[6];
  const float* bih0  = (const float*)d_in[7];
  const float* bhh0  = (const float*)d_in[8];
  const float* wih1  = (const float*)d_in[9];
  const float* whh1  = (const float*)d_in[10];
  const float* bih1  = (const float*)d_in[11];
  const float* bhh1  = (const float*)d_in[12];
  float* out = (float*)d_out;

  float* ws = (float*)d_ws;
  float* h0A = ws + WS_H0A;
  float* h0B = ws + WS_H0B;
  float* h1A = ws + WS_H1A;
  float* h1B = ws + WS_H1B;
  int* bar = (int*)(ws + WS_BAR);
  float* B1 = ws + WS_B1;
  float* te = ws + WS_TE;
  float* bcomp = ws + WS_BCOMP;
  float* wih04 = ws + WS_WIH04;
  float* enc4 = ws + WS_ENC4;
  float* Wa8 = ws + WS_WA8;
  float* Wf8 = ws + WS_WF8;

  hipMemsetAsync(ws, 0, (size_t)WS_B1 * sizeof(float), stream);

  k_b1<<<256, 256, 0, stream>>>(enc_w, dec_w, B1);
  k_te<<<1, 128, 0, stream>>>(enc_w, enc_b, dec_b, te);
  k_bcomp<<<8, 256, 0, stream>>>(wih0, te, bcomp);
  k_wa8<<<1024, 256, 0, stream>>>(wih0, B1, whh0, Wa8);
  k_wf8<<<1024, 256, 0, stream>>>(wih1, whh1, Wf8);
  k_wih04<<<256, 256, 0, stream>>>(wih0, wih04);
  k_enc4<<<16, 256, 0, stream>>>(enc_w, enc4);

  k_persist<<<NWG, 512, 0, stream>>>(
      x, enc4, enc_b, wih04, Wa8, Wf8, bih0, bhh0, bih1, bhh1,
      dec_w, dec_b, bcomp, h0A, h0B, h1A, h1B, bar, out);
}